// Round 4
// baseline (935.253 us; speedup 1.0000x reference)
//
#include <hip/hip_runtime.h>
#include <hip/hip_bf16.h>
#include <cstdint>

typedef float  f32x4 __attribute__((ext_vector_type(4)));
typedef short  s16x4 __attribute__((ext_vector_type(4)));
typedef short  s16x8 __attribute__((ext_vector_type(8)));
typedef __bf16 bf16x8 __attribute__((ext_vector_type(8)));

static __device__ __forceinline__ unsigned short f2bf(float f) {
  union { float f; unsigned u; } v; v.f = f;
  unsigned r = v.u + 0x7fffu + ((v.u >> 16) & 1u);   // RTNE
  return (unsigned short)(r >> 16);
}

static __device__ __forceinline__ f32x4 mfma16(bf16x8 a, bf16x8 b, f32x4 c) {
  return __builtin_amdgcn_mfma_f32_16x16x32_bf16(a, b, c, 0, 0, 0);
}

// ---------------------------------------------------------------------------
// k_mlp: fused per-ROI 2-layer MLP. Grid 512 = 64 ROIs x 8 HID-slices of 64.
// Tile: M=128 (batch) x N=64 (HID slice), K=2048 in 32 steps of BK=64.
// Register prefetch distance-2: loads for tile ks+2 issue right after the
// LDS store of tile ks, so the vmcnt wait covers a full step (~HBM latency).
// Epilogue: h = relu(C+b1) -> P = h @ W2slice -> atomicAdd(m1_parts[c], P/64)
// (8 partial slabs cut per-address atomic contention 512 -> 64).
// ---------------------------------------------------------------------------
__global__ __launch_bounds__(256, 2)
void k_mlp(const float* __restrict__ X, const float* __restrict__ W1,
           const float* __restrict__ b1, const float* __restrict__ W2,
           float* __restrict__ m1_parts)
{
  __shared__ short lds_a[128 * 72];   // [m][k] bf16, k padded 64->72
  __shared__ short lds_b[64 * 72];    // [n][k] bf16
  __shared__ short lds_h[128 * 72];   // layer2 A: [m][kh] bf16
  __shared__ short lds_w2[32 * 72];   // layer2 B: [o][kh] bf16 (o>=20 zero)
  __shared__ float biasS[64];

  const int bid = blockIdx.x;
  // XCD swizzle: the 8 c-slices of one r land on the same XCD
  const int r = (bid & 7) + ((bid >> 6) << 3);
  const int c = (bid >> 3) & 7;

  const float* xr = X + (long)r * (128 * 2048);
  const float* wr = W1 + (long)r * (2048 * 512) + c * 64;
  const float* bp = b1 + (long)r * 512 + c * 64;

  const int t = threadIdx.x;
  const int lane = t & 63;
  const int w = t >> 6;

  if (t < 64) biasS[t] = bp[t];

  // staging maps (BK=64)
  const int aRow = t >> 2;             // 0..63 (+64 for second group)
  const int aCol = (t & 3) * 4;        // within-row float offset, +16j
  const int bn   = t & 63;
  const int bk0  = w * 8;              // k-chunk base: 0,8,16,24 (+32 for g=1)

  f32x4 aR[2][2][4];
  float bR[2][2][8];

  auto loadTile = [&](int ks, int buf) {
    const float* xp = xr + (long)aRow * 2048 + ks * 64 + aCol;
#pragma unroll
    for (int j = 0; j < 4; j++) {
      aR[buf][0][j] = *(const f32x4*)(xp + 16 * j);
      aR[buf][1][j] = *(const f32x4*)(xp + 64 * 2048 + 16 * j);
    }
    const float* wp = wr + (long)(ks * 64 + bk0) * 512 + bn;
#pragma unroll
    for (int g = 0; g < 2; g++)
#pragma unroll
      for (int j = 0; j < 8; j++)
        bR[buf][g][j] = wp[(long)(g * 32 + j) * 512];
  };

  auto storeTile = [&](int buf) {
#pragma unroll
    for (int g = 0; g < 2; g++)
#pragma unroll
      for (int j = 0; j < 4; j++) {
        s16x4 v;
        v[0] = (short)f2bf(aR[buf][g][j][0]); v[1] = (short)f2bf(aR[buf][g][j][1]);
        v[2] = (short)f2bf(aR[buf][g][j][2]); v[3] = (short)f2bf(aR[buf][g][j][3]);
        *(s16x4*)&lds_a[(aRow + 64 * g) * 72 + aCol + 16 * j] = v;
      }
#pragma unroll
    for (int g = 0; g < 2; g++) {
      s16x8 v;
#pragma unroll
      for (int j = 0; j < 8; j++) v[j] = (short)f2bf(bR[buf][g][j]);
      *(s16x8*)&lds_b[bn * 72 + bk0 + g * 32] = v;
    }
  };

  // 4 waves as 2(m) x 2(n): each wave 64m x 32n; per step 4x2x2 MFMAs
  const int wm = w & 1, wn = w >> 1;
  const int mBase = wm * 64, nBase = wn * 32;
  const int lm = lane & 15, lg = lane >> 4;

  f32x4 acc[4][2];
#pragma unroll
  for (int i = 0; i < 4; i++)
#pragma unroll
    for (int j = 0; j < 2; j++) acc[i][j] = f32x4{0.f, 0.f, 0.f, 0.f};

  loadTile(0, 0);
  loadTile(1, 1);
  for (int ks = 0; ks < 32; ks++) {
    const int buf = ks & 1;
    __syncthreads();
    storeTile(buf);
    __syncthreads();
    if (ks + 2 < 32) loadTile(ks + 2, buf);
    bf16x8 af[2][4], bfr[2][2];
#pragma unroll
    for (int g = 0; g < 2; g++) {
#pragma unroll
      for (int i = 0; i < 4; i++)
        af[g][i] = *(const bf16x8*)&lds_a[(mBase + i * 16 + lm) * 72 + g * 32 + lg * 8];
#pragma unroll
      for (int j = 0; j < 2; j++)
        bfr[g][j] = *(const bf16x8*)&lds_b[(nBase + j * 16 + lm) * 72 + g * 32 + lg * 8];
    }
#pragma unroll
    for (int mi = 0; mi < 4; mi++)
#pragma unroll
      for (int ni = 0; ni < 2; ni++) {
        acc[mi][ni] = mfma16(af[0][mi], bfr[0][ni], acc[mi][ni]);
        acc[mi][ni] = mfma16(af[1][mi], bfr[1][ni], acc[mi][ni]);
      }
  }

  // h = relu(acc + b1) -> lds_h (bf16, A-layout [m][kh])
#pragma unroll
  for (int mi = 0; mi < 4; mi++)
#pragma unroll
    for (int ni = 0; ni < 2; ni++) {
      const int col = nBase + ni * 16 + lm;
      const float bv = biasS[col];
#pragma unroll
      for (int i = 0; i < 4; i++) {
        const int row = mBase + mi * 16 + lg * 4 + i;
        float v = acc[mi][ni][i] + bv;
        v = v > 0.f ? v : 0.f;
        lds_h[row * 72 + col] = (short)f2bf(v);
      }
    }
  // stage W2 slice [kh 0..63][o 0..19] -> lds_w2[o][kh], zero-pad o>=20
  {
    const float* w2r = W2 + (long)r * (512 * 20) + (long)c * 64 * 20;
#pragma unroll
    for (int i = 0; i < 8; i++) {
      const int idx = t * 8 + i;            // 0..2047
      const int o = idx >> 6, kh = idx & 63;
      const float v = (o < 20) ? w2r[(long)kh * 20 + o] : 0.f;
      lds_w2[o * 72 + kh] = (short)f2bf(v);
    }
  }
  __syncthreads();
  // layer-2: wave w -> m rows [w*32, w*32+32), o 0..31, K=64 (2 steps)
  f32x4 acc2[2][2];
#pragma unroll
  for (int i = 0; i < 2; i++)
#pragma unroll
    for (int j = 0; j < 2; j++) acc2[i][j] = f32x4{0.f, 0.f, 0.f, 0.f};
#pragma unroll
  for (int ks2 = 0; ks2 < 2; ks2++) {
    bf16x8 a0 = *(const bf16x8*)&lds_h[(w * 32 + lm) * 72 + ks2 * 32 + lg * 8];
    bf16x8 a1 = *(const bf16x8*)&lds_h[(w * 32 + 16 + lm) * 72 + ks2 * 32 + lg * 8];
    bf16x8 b0 = *(const bf16x8*)&lds_w2[lm * 72 + ks2 * 32 + lg * 8];
    bf16x8 b1v = *(const bf16x8*)&lds_w2[(16 + lm) * 72 + ks2 * 32 + lg * 8];
    acc2[0][0] = mfma16(a0, b0, acc2[0][0]);
    acc2[0][1] = mfma16(a0, b1v, acc2[0][1]);
    acc2[1][0] = mfma16(a1, b0, acc2[1][0]);
    acc2[1][1] = mfma16(a1, b1v, acc2[1][1]);
  }
  float* mp = m1_parts + (long)c * 2560;
#pragma unroll
  for (int mi = 0; mi < 2; mi++)
#pragma unroll
    for (int ni = 0; ni < 2; ni++)
#pragma unroll
      for (int i = 0; i < 4; i++) {
        const int m = w * 32 + mi * 16 + lg * 4 + i;
        const int o = ni * 16 + lm;
        if (o < 20)
          atomicAdd(&mp[m * 20 + o], acc2[mi][ni][i] * (1.f / 64.f));
      }
}

// ---------------------------------------------------------------------------
// gemm_n64: out[:, c*64 : +64] = act(X[128,K] @ W[K,N] + bias), prefetch-2
// ---------------------------------------------------------------------------
template<int RELU>
__global__ __launch_bounds__(256, 2)
void gemm_n64(const float* __restrict__ X, int ldx,
              const float* __restrict__ W, int ldw,
              const float* __restrict__ bias,
              float* __restrict__ out, int ldo, int kSteps)
{
  __shared__ short lds_a[128 * 72];
  __shared__ short lds_b[64 * 72];
  __shared__ float biasS[64];

  const int c = blockIdx.x;
  const int t = threadIdx.x;
  const int lane = t & 63;
  const int w = t >> 6;

  if (t < 64) biasS[t] = bias[c * 64 + t];

  const int aRow = t >> 2;
  const int aCol = (t & 3) * 4;
  const int bn   = t & 63;
  const int bk0  = w * 8;

  f32x4 aR[2][2][4];
  float bR[2][2][8];

  auto loadTile = [&](int ks, int buf) {
    const float* xp = X + (long)aRow * ldx + ks * 64 + aCol;
#pragma unroll
    for (int j = 0; j < 4; j++) {
      aR[buf][0][j] = *(const f32x4*)(xp + 16 * j);
      aR[buf][1][j] = *(const f32x4*)(xp + (long)64 * ldx + 16 * j);
    }
    const float* wp = W + (long)(ks * 64 + bk0) * ldw + c * 64 + bn;
#pragma unroll
    for (int g = 0; g < 2; g++)
#pragma unroll
      for (int j = 0; j < 8; j++)
        bR[buf][g][j] = wp[(long)(g * 32 + j) * ldw];
  };

  auto storeTile = [&](int buf) {
#pragma unroll
    for (int g = 0; g < 2; g++)
#pragma unroll
      for (int j = 0; j < 4; j++) {
        s16x4 v;
        v[0] = (short)f2bf(aR[buf][g][j][0]); v[1] = (short)f2bf(aR[buf][g][j][1]);
        v[2] = (short)f2bf(aR[buf][g][j][2]); v[3] = (short)f2bf(aR[buf][g][j][3]);
        *(s16x4*)&lds_a[(aRow + 64 * g) * 72 + aCol + 16 * j] = v;
      }
#pragma unroll
    for (int g = 0; g < 2; g++) {
      s16x8 v;
#pragma unroll
      for (int j = 0; j < 8; j++) v[j] = (short)f2bf(bR[buf][g][j]);
      *(s16x8*)&lds_b[bn * 72 + bk0 + g * 32] = v;
    }
  };

  const int wm = w & 1, wn = w >> 1;
  const int mBase = wm * 64, nBase = wn * 32;
  const int lm = lane & 15, lg = lane >> 4;

  f32x4 acc[4][2];
#pragma unroll
  for (int i = 0; i < 4; i++)
#pragma unroll
    for (int j = 0; j < 2; j++) acc[i][j] = f32x4{0.f, 0.f, 0.f, 0.f};

  loadTile(0, 0);
  loadTile(1, 1);
  for (int ks = 0; ks < kSteps; ks++) {
    const int buf = ks & 1;
    __syncthreads();
    storeTile(buf);
    __syncthreads();
    if (ks + 2 < kSteps) loadTile(ks + 2, buf);
    bf16x8 af[2][4], bfr[2][2];
#pragma unroll
    for (int g = 0; g < 2; g++) {
#pragma unroll
      for (int i = 0; i < 4; i++)
        af[g][i] = *(const bf16x8*)&lds_a[(mBase + i * 16 + lm) * 72 + g * 32 + lg * 8];
#pragma unroll
      for (int j = 0; j < 2; j++)
        bfr[g][j] = *(const bf16x8*)&lds_b[(nBase + j * 16 + lm) * 72 + g * 32 + lg * 8];
    }
#pragma unroll
    for (int mi = 0; mi < 4; mi++)
#pragma unroll
      for (int ni = 0; ni < 2; ni++) {
        acc[mi][ni] = mfma16(af[0][mi], bfr[0][ni], acc[mi][ni]);
        acc[mi][ni] = mfma16(af[1][mi], bfr[1][ni], acc[mi][ni]);
      }
  }

  float* outp = out + c * 64;
#pragma unroll
  for (int mi = 0; mi < 4; mi++)
#pragma unroll
    for (int ni = 0; ni < 2; ni++) {
      const int col = nBase + ni * 16 + lm;
      const float bv = biasS[col];
#pragma unroll
      for (int i = 0; i < 4; i++) {
        const int row = mBase + mi * 16 + lg * 4 + i;
        float v = acc[mi][ni][i] + bv;
        if (RELU) v = v > 0.f ? v : 0.f;
        outp[(long)row * ldo + col] = v;
      }
    }
}

// zero the 8 m1 partial slabs
__global__ void k_zero(float* __restrict__ p) {
  const int i = blockIdx.x * blockDim.x + threadIdx.x;
  if (i < 8 * 2560) p[i] = 0.f;
}

// fused: m1 = sum(parts) + mean_r(b2); g1 = relu(m1@Wg1+bg1);
//        g2 = relu(g1@Wg2+bg2). Single block (tiny sizes).
__global__ void k_gcn(const float* __restrict__ parts, const float* __restrict__ b2,
                      const float* __restrict__ Wg1, const float* __restrict__ bg1,
                      const float* __restrict__ Wg2, const float* __restrict__ bg2,
                      float* __restrict__ g2)
{
  __shared__ float s_m1[2560];
  __shared__ float s_g1[8192];
  __shared__ float s_bm[20];
  const int t = threadIdx.x;
  if (t < 20) {
    float s = 0.f;
    for (int r = 0; r < 64; r++) s += b2[r * 20 + t];
    s_bm[t] = s * (1.f / 64.f);
  }
  __syncthreads();
  for (int i = t; i < 2560; i += 256) {
    float s = s_bm[i % 20];
#pragma unroll
    for (int p = 0; p < 8; p++) s += parts[p * 2560 + i];
    s_m1[i] = s;
  }
  __syncthreads();
  for (int i = t; i < 8192; i += 256) {
    const int b = i >> 6, j = i & 63;
    float s = bg1[j];
#pragma unroll
    for (int k = 0; k < 20; k++) s += s_m1[b * 20 + k] * Wg1[k * 64 + j];
    s_g1[i] = s > 0.f ? s : 0.f;
  }
  __syncthreads();
  for (int i = t; i < 16384; i += 256) {
    const int b = i >> 7, j = i & 127;
    float s = bg2[j];
#pragma unroll
    for (int k = 0; k < 64; k++) s += s_g1[b * 64 + k] * Wg2[k * 128 + j];
    g2[i] = s > 0.f ? s : 0.f;
  }
}

extern "C" void kernel_launch(void* const* d_in, const int* in_sizes, int n_in,
                              void* d_out, int out_size, void* d_ws, size_t ws_size,
                              hipStream_t stream)
{
  const float* x   = (const float*)d_in[0];
  const float* W1  = (const float*)d_in[3];
  const float* b1  = (const float*)d_in[4];
  const float* W2  = (const float*)d_in[5];
  const float* b2  = (const float*)d_in[6];
  const float* Wg1 = (const float*)d_in[7];
  const float* bg1 = (const float*)d_in[8];
  const float* Wg2 = (const float*)d_in[9];
  const float* bg2 = (const float*)d_in[10];
  const float* Wf1 = (const float*)d_in[11];
  const float* bf1 = (const float*)d_in[12];
  const float* Wf2 = (const float*)d_in[13];
  const float* bf2 = (const float*)d_in[14];
  const float* Wo  = (const float*)d_in[15];
  const float* bo  = (const float*)d_in[16];
  float* out = (float*)d_out;

  float* ws = (float*)d_ws;
  float* m1p = ws;           // 8*2560 floats (partial slabs)
  float* g2  = ws + 24576;   // 16384
  float* y1  = ws + 49152;   // 65536
  float* y2  = ws + 131072;  // 131072

  k_zero<<<80, 256, 0, stream>>>(m1p);
  // dominant: per-ROI 2-layer MLP, 64 ROIs x 8 HID-slices
  k_mlp<<<512, 256, 0, stream>>>(x, W1, b1, W2, m1p);
  // collapsed-GCN (uniform degree => mean+linear), fused fc1+fc2
  k_gcn<<<1, 256, 0, stream>>>(m1p, b2, Wg1, bg1, Wg2, bg2, g2);
  gemm_n64<1><<<8,   256, 0, stream>>>(g2, 128,  Wf1, 512,  bf1, y1, 512, 2);
  gemm_n64<1><<<16,  256, 0, stream>>>(y1, 512,  Wf2, 1024, bf2, y2, 1024, 8);
  gemm_n64<0><<<100, 256, 0, stream>>>(y2, 1024, Wo,  6400, bo,  out, 6400, 16);
}